// Round 6
// baseline (454.245 us; speedup 1.0000x reference)
//
#include <hip/hip_runtime.h>
#include <hip/hip_bf16.h>

#define HDIM 512
#define BDIM 1024
#define DDIM 256

typedef _Float16 half8 __attribute__((ext_vector_type(8)));
typedef float f32x4 __attribute__((ext_vector_type(4)));

__device__ __forceinline__ float ftanh(float x) {
    float e = __expf(2.0f * x);
    return 1.0f - 2.0f / (e + 1.0f);
}

__device__ __forceinline__ void gl_lds16(const _Float16* src, _Float16* dst) {
    __builtin_amdgcn_global_load_lds((const __attribute__((address_space(1))) void*)src,
                                     (__attribute__((address_space(3))) void*)dst,
                                     16, 0, 0);
}

// K0: Wah f32 [512][512] -> W16 fp16 chunked: chunk c = g-cols [c*16, c*16+16),
// granule (kb*64 + g*4 + kp) holds Wah[c*16+g][kb*32 + kp*8 .. +8].
// Linear DMA image; B-frag read = 64 consecutive granules per wave.
__global__ __launch_bounds__(256) void k_convertW(const float* __restrict__ Wah,
                                                  _Float16* __restrict__ W16) {
    int n = blockIdx.x * 256 + threadIdx.x;   // granule id, 32768 total
    int chunk = n >> 10, r = n & 1023;
    int kb = r >> 6, g = (r >> 2) & 15, kp = r & 3;
    const float* src = Wah + (size_t)(chunk * 16 + g) * 512 + kb * 32 + kp * 8;
    float4 v0 = *(const float4*)src;
    float4 v1 = *(const float4*)(src + 4);
    half8 h;
    h[0] = (_Float16)v0.x; h[1] = (_Float16)v0.y; h[2] = (_Float16)v0.z; h[3] = (_Float16)v0.w;
    h[4] = (_Float16)v1.x; h[5] = (_Float16)v1.y; h[6] = (_Float16)v1.z; h[7] = (_Float16)v1.w;
    *(half8*)&W16[(size_t)n * 8] = h;
}

// K1: qb[b,g] = concat(h_tilde,c_t)[b,:] . Waq[g,:] + ba[g]   (fp32)
__global__ __launch_bounds__(256) void k_qproj(const float* __restrict__ h_tilde,
                                               const float* __restrict__ c_t,
                                               const float* __restrict__ Waq,
                                               const float* __restrict__ ba,
                                               float* __restrict__ qb) {
    __shared__ float qs[4][1024];
    int t = threadIdx.x;
    int b0 = blockIdx.x * 4;
    #pragma unroll
    for (int p = 0; p < 4; p++) {
        int f4 = t + p * 256;
        int e = f4 * 4;
        int row = e >> 10, k = e & 1023;
        float4 v;
        if (k < 512) v = *(const float4*)&h_tilde[(b0 + row) * 512 + k];
        else         v = *(const float4*)&c_t[(b0 + row) * 512 + k - 512];
        *(float4*)&qs[row][k] = v;
    }
    __syncthreads();
    int g0 = t, g1 = t + 256;
    float acc0[4] = {0.f, 0.f, 0.f, 0.f};
    float acc1[4] = {0.f, 0.f, 0.f, 0.f};
    const float4* w0p = (const float4*)&Waq[(size_t)g0 * 1024];
    const float4* w1p = (const float4*)&Waq[(size_t)g1 * 1024];
    #pragma unroll 4
    for (int k4 = 0; k4 < 256; k4++) {
        float4 w0 = w0p[k4];
        float4 w1 = w1p[k4];
        #pragma unroll
        for (int bb = 0; bb < 4; bb++) {
            float4 q = *(const float4*)&qs[bb][k4 * 4];
            acc0[bb] += q.x * w0.x + q.y * w0.y + q.z * w0.z + q.w * w0.w;
            acc1[bb] += q.x * w1.x + q.y * w1.y + q.z * w1.z + q.w * w1.w;
        }
    }
    #pragma unroll
    for (int bb = 0; bb < 4; bb++) {
        qb[(b0 + bb) * 512 + g0] = acc0[bb] + ba[g0];
        qb[(b0 + bb) * 512 + g1] = acc1[bb] + ba[g1];
    }
}

// K2 (fused): one block per b. 512 thr / 8 waves, wave owns 32 of the 256 rows.
// X = hist[b] loaded ONCE (HBM) into registers as fp16 A-frags (afr[2][16]).
// W streamed through LDS in 32 chunks of 16 g-cols (16 KB, dbuf, linear DMA).
// Per chunk: 32 MFMA -> tanh+qb, dot v folds into S. Then in-block softmax
// over D=256, then e_t computed FROM afr (no second hist pass), alpha+e_t out.
__global__ __launch_bounds__(512, 2) void k_fused(const float* __restrict__ hist,
                                                  const float* __restrict__ qb,
                                                  const _Float16* __restrict__ W16,
                                                  const float* __restrict__ v_t,
                                                  float* __restrict__ out) {
    __shared__ _Float16 Wb[2][8192];   // 16 KB each
    __shared__ float qbs[512];
    __shared__ float vsh[512];
    __shared__ float lsh[256];         // logits
    __shared__ float ash[256];         // alpha
    __shared__ float wredM[8];
    __shared__ float wredS[8];
    __shared__ float esh[8][512];      // per-wave e_t partials (16 KB)

    int t = threadIdx.x;
    int w = t >> 6, lane = t & 63, l15 = lane & 15, l4 = lane >> 4;
    int b = blockIdx.x;
    size_t m_base = (size_t)b * 256;

    qbs[t] = qb[b * 512 + t];
    vsh[t] = v_t[t];

    // issue DMA for chunk 0 (completes during X-load phase)
    // wave w fills segments {2w, 2w+1} of the 16 x 1KB chunk image
    #pragma unroll
    for (int s = 0; s < 2; s++)
        gl_lds16(W16 + ((size_t)(w * 2 + s) * 64 + lane) * 8,
                 &Wb[0][(w * 2 + s) * 512]);

    // X-load: afr[mf][kb] = hist[b][w*32 + mf*16 + l15][kb*32 + l4*8 .. +8] fp16
    half8 afr[2][16];
    const float* xb = hist + (m_base + w * 32 + l15) * 512 + l4 * 8;
    #pragma unroll
    for (int kb = 0; kb < 16; kb++) {
        #pragma unroll
        for (int mf = 0; mf < 2; mf++) {
            const float* p = xb + mf * 16 * 512 + kb * 32;
            float4 v0 = *(const float4*)p;
            float4 v1 = *(const float4*)(p + 4);
            half8 h;
            h[0] = (_Float16)v0.x; h[1] = (_Float16)v0.y; h[2] = (_Float16)v0.z; h[3] = (_Float16)v0.w;
            h[4] = (_Float16)v1.x; h[5] = (_Float16)v1.y; h[6] = (_Float16)v1.z; h[7] = (_Float16)v1.w;
            afr[mf][kb] = h;
        }
    }

    float S[2][4] = {{0.f, 0.f, 0.f, 0.f}, {0.f, 0.f, 0.f, 0.f}};

    __syncthreads();   // drains DMA chunk 0 + qbs/vsh stores

    const int lofs = (l15 * 4 + l4) * 8;   // lane's granule within each kb-block

    for (int c = 0; c < 32; c++) {
        int cur = c & 1;
        if (c < 31) {
            const _Float16* wc = W16 + (size_t)(c + 1) * 8192;
            _Float16* wd = Wb[cur ^ 1];
            #pragma unroll
            for (int s = 0; s < 2; s++)
                gl_lds16(wc + ((size_t)(w * 2 + s) * 64 + lane) * 8,
                         &wd[(w * 2 + s) * 512]);
        }
        const _Float16* bufp = &Wb[cur][lofs];
        f32x4 tac0 = (f32x4){0.f, 0.f, 0.f, 0.f};
        f32x4 tac1 = (f32x4){0.f, 0.f, 0.f, 0.f};
        __builtin_amdgcn_s_setprio(1);
        #pragma unroll
        for (int kb = 0; kb < 16; kb++) {
            half8 bf = *(const half8*)(bufp + kb * 512);
            tac0 = __builtin_amdgcn_mfma_f32_16x16x32_f16(afr[0][kb], bf, tac0, 0, 0, 0);
            tac1 = __builtin_amdgcn_mfma_f32_16x16x32_f16(afr[1][kb], bf, tac1, 0, 0, 0);
        }
        __builtin_amdgcn_s_setprio(0);
        float qv = qbs[c * 16 + l15];
        float vv = vsh[c * 16 + l15];
        #pragma unroll
        for (int j = 0; j < 4; j++) {
            S[0][j] += ftanh(tac0[j] + qv) * vv;
            S[1][j] += ftanh(tac1[j] + qv) * vv;
        }
        __syncthreads();   // DMA(c+1) done; all waves done with buf[cur]
    }

    // ---- logits: reduce S over l15, write lsh ----
    #pragma unroll
    for (int mf = 0; mf < 2; mf++) {
        #pragma unroll
        for (int j = 0; j < 4; j++) {
            float s = S[mf][j];
            s += __shfl_xor(s, 1, 64);
            s += __shfl_xor(s, 2, 64);
            s += __shfl_xor(s, 4, 64);
            s += __shfl_xor(s, 8, 64);
            if (l15 == 0) lsh[w * 32 + mf * 16 + l4 * 4 + j] = s;
        }
    }
    __syncthreads();

    // ---- softmax over D=256 (all threads run; waves 4-7 mirror 0-3) ----
    float lv = lsh[t & 255];
    float m = lv;
    m = fmaxf(m, __shfl_xor(m, 1, 64));
    m = fmaxf(m, __shfl_xor(m, 2, 64));
    m = fmaxf(m, __shfl_xor(m, 4, 64));
    m = fmaxf(m, __shfl_xor(m, 8, 64));
    m = fmaxf(m, __shfl_xor(m, 16, 64));
    m = fmaxf(m, __shfl_xor(m, 32, 64));
    if (lane == 0 && w < 4) wredM[w] = m;
    __syncthreads();
    m = fmaxf(fmaxf(wredM[0], wredM[1]), fmaxf(wredM[2], wredM[3]));
    float e = __expf(lv - m);
    float ssum = e;
    ssum += __shfl_xor(ssum, 1, 64);
    ssum += __shfl_xor(ssum, 2, 64);
    ssum += __shfl_xor(ssum, 4, 64);
    ssum += __shfl_xor(ssum, 8, 64);
    ssum += __shfl_xor(ssum, 16, 64);
    ssum += __shfl_xor(ssum, 32, 64);
    if (lane == 0 && w < 4) wredS[w] = ssum;
    __syncthreads();
    ssum = wredS[0] + wredS[1] + wredS[2] + wredS[3];
    float a = e / ssum;
    if (t < 256) {
        ash[t] = a;
        out[BDIM * HDIM + b * 256 + t] = a;   // alpha
    }
    __syncthreads();

    // ---- e_t from afr registers: e_t[h] = sum_d alpha[d] * X16[d][h] ----
    float al0 = ash[w * 32 + l15];
    float al1 = ash[w * 32 + 16 + l15];
    #pragma unroll
    for (int kb = 0; kb < 16; kb++) {
        float ep[8];
        half8 x0 = afr[0][kb];
        half8 x1 = afr[1][kb];
        #pragma unroll
        for (int e2 = 0; e2 < 8; e2++)
            ep[e2] = al0 * (float)x0[e2] + al1 * (float)x1[e2];
        #pragma unroll
        for (int e2 = 0; e2 < 8; e2++) {
            ep[e2] += __shfl_xor(ep[e2], 1, 64);
            ep[e2] += __shfl_xor(ep[e2], 2, 64);
            ep[e2] += __shfl_xor(ep[e2], 4, 64);
            ep[e2] += __shfl_xor(ep[e2], 8, 64);
        }
        if (l15 == 0) {
            #pragma unroll
            for (int e2 = 0; e2 < 8; e2++)
                esh[w][kb * 32 + l4 * 8 + e2] = ep[e2];
        }
    }
    __syncthreads();
    float r = 0.f;
    #pragma unroll
    for (int ww = 0; ww < 8; ww++) r += esh[ww][t];
    out[(size_t)b * 512 + t] = r;   // e_t
}

extern "C" void kernel_launch(void* const* d_in, const int* in_sizes, int n_in,
                              void* d_out, int out_size, void* d_ws, size_t ws_size,
                              hipStream_t stream) {
    const float* h_tilde = (const float*)d_in[0];
    const float* c_t     = (const float*)d_in[1];
    const float* hist    = (const float*)d_in[2];
    const float* Waq     = (const float*)d_in[3];
    const float* Wah     = (const float*)d_in[4];
    const float* ba      = (const float*)d_in[5];
    const float* v_t     = (const float*)d_in[6];
    float* out = (float*)d_out;

    char* ws = (char*)d_ws;
    float*    qb  = (float*)ws;                               // 2 MB
    _Float16* W16 = (_Float16*)(ws + (2u << 20));             // 512 KB

    k_convertW<<<128, 256, 0, stream>>>(Wah, W16);
    k_qproj<<<256, 256, 0, stream>>>(h_tilde, c_t, Waq, ba, qb);
    k_fused<<<1024, 512, 0, stream>>>(hist, qb, W16, v_t, out);
}